// Round 1
// 156.723 us; speedup vs baseline: 1.0079x; 1.0079x over previous
//
#include <hip/hip_runtime.h>
#include <hip/hip_bf16.h>
#include <math.h>

#define LSEQ 2048
#define DMODEL 256
#define NH 8
#define HD 32

typedef __attribute__((ext_vector_type(8))) short bf16x8;
typedef __attribute__((ext_vector_type(4))) float f32x4;

#define MFMA __builtin_amdgcn_mfma_f32_16x16x32_bf16

__device__ __forceinline__ short f2bf(float x) {
  __hip_bfloat16 h = __float2bfloat16(x);
  return __builtin_bit_cast(short, h);
}
__device__ __forceinline__ float bf2f(short s) {
  __hip_bfloat16 h = __builtin_bit_cast(__hip_bfloat16, s);
  return __bfloat162float(h);
}
__device__ __forceinline__ short bftrunc(float x) {      // truncating f32->bf16
  return (short)(__builtin_bit_cast(unsigned int, x) >> 16);
}
// bare v_exp_f32 (2^x) — skip OCML denormal fixup (underflowed p contribute 0)
__device__ __forceinline__ float fexp2(float x) {
#if __has_builtin(__builtin_amdgcn_exp2f)
  return __builtin_amdgcn_exp2f(x);
#else
  return __expf(x * 0.6931471805599453f);
#endif
}
__device__ __forceinline__ float flog2(float x) {
#if __has_builtin(__builtin_amdgcn_logf)
  return __builtin_amdgcn_logf(x);
#else
  return __logf(x) * 1.4426950408889634f;
#endif
}

// ---- aux: Wqkv -> bf16, Wo -> split bf16, prior tables ----
__global__ __launch_bounds__(256) void aux_kernel(
    const float* __restrict__ Wq, const float* __restrict__ Wk,
    const float* __restrict__ Wv, const float* __restrict__ Wo,
    const float* __restrict__ u,
    short* __restrict__ Wh,
    short* __restrict__ Woh, short* __restrict__ Wol,
    float* __restrict__ Eb, float* __restrict__ Zb)
{
  __shared__ float Cs[LSEQ];
  __shared__ float part[256];
  const int tid = threadIdx.x;
  if (blockIdx.x < 256) {
    const int i4 = (blockIdx.x * 256 + tid) * 4;
    if (i4 < 196608) {
      int row = i4 >> 8, col = i4 & 255;
      const float* W = (row < 256) ? Wq : (row < 512) ? Wk : Wv;
      float4 v = *(const float4*)(W + (row & 255) * 256 + col);
      *(short4*)(Wh + i4) = make_short4(f2bf(v.x), f2bf(v.y), f2bf(v.z), f2bf(v.w));
    } else {
      int j = i4 - 196608;
      float4 v = *(const float4*)(Wo + j);
      short h0 = f2bf(v.x), h1 = f2bf(v.y), h2 = f2bf(v.z), h3 = f2bf(v.w);
      *(short4*)(Woh + j) = make_short4(h0, h1, h2, h3);
      *(short4*)(Wol + j) = make_short4(bftrunc(v.x - bf2f(h0)), bftrunc(v.y - bf2f(h1)),
                                        bftrunc(v.z - bf2f(h2)), bftrunc(v.w - bf2f(h3)));
    }
    return;
  }
  const int h = blockIdx.x - 256;
  const float uu = u[h];
  const float den = 2.0f * (uu * uu + 1e-6f);
  float e[8]; float run = 0.f;
  const int base = tid * 8;
#pragma unroll
  for (int j = 0; j < 8; ++j) {
    float d = (float)(base + j);
    e[j] = __expf(-(d * d) / den);
    run += e[j];
  }
  part[tid] = run;
  __syncthreads();
  for (int off = 1; off < 256; off <<= 1) {
    float v = (tid >= off) ? part[tid - off] : 0.f;
    __syncthreads();
    part[tid] += v;
    __syncthreads();
  }
  float c = part[tid] - run;
#pragma unroll
  for (int j = 0; j < 8; ++j) {
    c += e[j];
    Cs[base + j] = c;
    Eb[h * LSEQ + base + j] = e[j];
  }
  __syncthreads();
  const float E0 = Cs[0];
  for (int i = tid; i < LSEQ; i += 256) {
    float s = Cs[i] + Cs[LSEQ - 1 - i] - E0;
    Zb[h * LSEQ + i] = 1.0f / (s + 1e-6f);
  }
}

// ---------------- fused QKV GEMM (pure bf16 MFMA, LDS-free) ------------------
__global__ __launch_bounds__(256) void qkv_gemm(
    const float* __restrict__ x,
    const short* __restrict__ Bh,
    const float* __restrict__ bq, const float* __restrict__ bk,
    const float* __restrict__ bv,
    short* __restrict__ Qf, short* __restrict__ Kf, short* __restrict__ Vf)
{
  const int tid = threadIdx.x, w = tid >> 6, lane = tid & 63;
  const int l15 = lane & 15, q4 = lane >> 4;
  const int m0 = blockIdx.x * 64, n0 = blockIdx.y * 64;
  const int mrow = m0 + w * 16 + l15;
  f32x4 acc[4] = {{0,0,0,0},{0,0,0,0},{0,0,0,0},{0,0,0,0}};
  for (int k0 = 0; k0 < 256; k0 += 32) {
    const float* xp = &x[(size_t)mrow * 256 + k0 + q4 * 8];
    float4 a = *(const float4*)xp;
    float4 c = *(const float4*)(xp + 4);
    bf16x8 ah;
    ah[0] = f2bf(a.x); ah[1] = f2bf(a.y); ah[2] = f2bf(a.z); ah[3] = f2bf(a.w);
    ah[4] = f2bf(c.x); ah[5] = f2bf(c.y); ah[6] = f2bf(c.z); ah[7] = f2bf(c.w);
#pragma unroll
    for (int nt = 0; nt < 4; ++nt) {
      const size_t bi = (size_t)(n0 + nt * 16 + l15) * 256 + k0 + q4 * 8;
      bf16x8 bh = *(const bf16x8*)&Bh[bi];
      acc[nt] = MFMA(ah, bh, acc[nt], 0, 0, 0);
    }
  }
  const int type = n0 >> 8;        // 0=Q 1=K 2=V
  const int n0l = n0 & 255;
  const float* bias = (type == 0) ? bq : (type == 1) ? bk : bv;
  const float qls = 0.25503489f;   // (1/sqrt(32)) * log2(e)
#pragma unroll
  for (int nt = 0; nt < 4; ++nt) {
    const int col = n0l + nt * 16 + l15;
    const float bvv = bias[col];
    const int hh = col >> 5, dloc = col & 31;
#pragma unroll
    for (int r = 0; r < 4; ++r) {
      const int m = m0 + w * 16 + q4 * 4 + r;
      float v = acc[nt][r] + bvv;
      const int bb = m >> 11, mm = m & 2047, rr = mm & 15;
      if (type == 2) {
        const int kt128 = mm >> 7, low7 = mm & 127;
        const int wv = (low7 >> 4) & 3, ph = low7 >> 6;
        const int c = ph * 16 + rr;
        const size_t idx =
          ((((((size_t)bb * 8 + hh) * 16 + kt128) * 4 + wv) * 2 + (dloc >> 4)) * 64
           + (c >> 3) * 16 + (dloc & 15)) * 8 + (c & 7);
        Vf[idx] = f2bf(v);
      } else if (type == 0) {
        const int qblk = mm >> 5, rg = (mm >> 4) & 1;
        const size_t idx =
          (((((size_t)bb * 8 + hh) * 64 + qblk) * 2 + rg) * 64
           + (dloc >> 3) * 16 + rr) * 8 + (dloc & 7);
        Qf[idx] = f2bf(v * qls);
      } else {
        const int g = mm >> 4;
        const size_t idx =
          ((((size_t)bb * 8 + hh) * 128 + g) * 64
           + (dloc >> 3) * 16 + rr) * 8 + (dloc & 7);
        Kf[idx] = f2bf(v);
      }
    }
  }
}

// ---------------- output GEMM (split-bf16 MFMA, fp32 out) --------------------
__global__ __launch_bounds__(256) void out_gemm(
    const short* __restrict__ Ah, const short* __restrict__ Al,
    const short* __restrict__ Bh, const short* __restrict__ Bl,
    const float* __restrict__ bias, float* __restrict__ C)
{
  const int tid = threadIdx.x, w = tid >> 6, lane = tid & 63;
  const int l15 = lane & 15, q4 = lane >> 4;
  const int m0 = blockIdx.x * 64, n0 = blockIdx.y * 64;
  const int mrow = m0 + w * 16 + l15;
  f32x4 acc[4] = {{0,0,0,0},{0,0,0,0},{0,0,0,0},{0,0,0,0}};
  for (int k0 = 0; k0 < 256; k0 += 32) {
    bf16x8 ah = *(const bf16x8*)&Ah[(size_t)mrow * 256 + k0 + q4 * 8];
    bf16x8 al = *(const bf16x8*)&Al[(size_t)mrow * 256 + k0 + q4 * 8];
#pragma unroll
    for (int nt = 0; nt < 4; ++nt) {
      const size_t bi = (size_t)(n0 + nt * 16 + l15) * 256 + k0 + q4 * 8;
      bf16x8 bh = *(const bf16x8*)&Bh[bi];
      bf16x8 bl = *(const bf16x8*)&Bl[bi];
      acc[nt] = MFMA(ah, bh, acc[nt], 0, 0, 0);
      acc[nt] = MFMA(al, bh, acc[nt], 0, 0, 0);
      acc[nt] = MFMA(ah, bl, acc[nt], 0, 0, 0);
    }
  }
#pragma unroll
  for (int nt = 0; nt < 4; ++nt) {
    const int col = n0 + nt * 16 + l15;
    const float bvv = bias[col];
#pragma unroll
    for (int r = 0; r < 4; ++r) {
      const int m = m0 + w * 16 + q4 * 4 + r;
      C[(size_t)m * 256 + col] = acc[nt][r] + bvv;
    }
  }
}

// ---------------- barrier-free MFMA flash attention + discrepancy ------------
// 16-row q-tiles: 2048 blocks = 8 blocks/CU (grid-limited full occupancy).
// NO global atomics: each block's per-k disc column partial is written exactly
// once (bf16) into its own Dp row; disc_reduce sums the 1024 rows per batch.
// dcol LDS buffer gone; in-loop LDS atomics replaced by the same exactly-once
// property (each (w,ph,iter,l15) owns a distinct k).
__global__ __launch_bounds__(256, 8) void attn_kernel(
    const short* __restrict__ Qf, const short* __restrict__ Kf,
    const short* __restrict__ Vf,
    const float* __restrict__ Eb, const float* __restrict__ Zb,
    short* __restrict__ Ohb, short* __restrict__ Olb,
    short* __restrict__ Dp)
{
  __shared__ short Pt[4][16][40];   // per-wave P tile (reused as Ored)
  __shared__ float Elds[192];
  __shared__ float lpart[4][16];
  __shared__ float izlds[16];

  const int tid = threadIdx.x, w = tid >> 6, lane = tid & 63;
  const int l15 = lane & 15, q4 = lane >> 4;
  // ---- XCD swizzle: flat = x + 128*(y + 8*z); xcd = flat&7 ----
  const int flat = blockIdx.x + 128 * (blockIdx.y + 8 * blockIdx.z);
  const int slot = flat >> 3;                       // 0..255 per xcd
  const int g = (flat & 7) | ((slot >> 7) << 3);    // bh 0..15: same (b,h) stays on one XCD
  const int h = g & 7, b = g >> 3;
  const int qslot = slot & 127, q0 = qslot * 16;
  const int bh = b * NH + h;

  if (tid < 192) Elds[tid] = Eb[h * LSEQ + tid];
  if (tid < 16)  izlds[tid] = Zb[h * LSEQ + q0 + tid];

  const bf16x8* Qf8 = (const bf16x8*)Qf;
  const bf16x8* Kf8 = (const bf16x8*)Kf;
  const bf16x8* Vf8 = (const bf16x8*)Vf;

  bf16x8 qh = Qf8[((size_t)bh * 128 + qslot) * 64 + lane];
  __syncthreads();

  const size_t kfb = (size_t)bh * 128;   // K group base
  const size_t vfb = (size_t)bh * 16;    // V kt128 base

  // ---- pass 1: per-wave k-partial row sums of 2^s ----
  float lac[4] = {0.f, 0.f, 0.f, 0.f};
#pragma unroll 2
  for (int kt = 0; kt < LSEQ; kt += 128) {
    bf16x8 k0 = Kf8[(kfb + (kt >> 4) + w) * 64 + lane];
    bf16x8 k1 = Kf8[(kfb + (kt >> 4) + 4 + w) * 64 + lane];
    f32x4 s0 = {0.f, 0.f, 0.f, 0.f};
    s0 = MFMA(qh, k0, s0, 0, 0, 0);
    f32x4 s1 = {0.f, 0.f, 0.f, 0.f};
    s1 = MFMA(qh, k1, s1, 0, 0, 0);
#pragma unroll
    for (int r = 0; r < 4; ++r) lac[r] += fexp2(s0[r]) + fexp2(s1[r]);
  }
#pragma unroll
  for (int r = 0; r < 4; ++r) {
    float v = lac[r];
    v += __shfl_xor(v, 1); v += __shfl_xor(v, 2);
    v += __shfl_xor(v, 4); v += __shfl_xor(v, 8);
    lac[r] = v;
  }
  if (l15 == 0) {
#pragma unroll
    for (int r = 0; r < 4; ++r) lpart[w][q4 * 4 + r] = lac[r];
  }
  __syncthreads();
  f32x4 sinit;
#pragma unroll
  for (int r = 0; r < 4; ++r) {
    const int qi = q4 * 4 + r;
    sinit[r] = -flog2(lpart[0][qi] + lpart[1][qi] + lpart[2][qi] + lpart[3][qi]);
  }

  // ---- pass 2: p = 2^(s + sinit), disc column partials, O += P*V ----
  const size_t drow = (size_t)(g * 128 + qslot) * LSEQ;
  f32x4 oacc[2] = {{0,0,0,0},{0,0,0,0}};
#pragma unroll 2
  for (int kt = 0; kt < LSEQ; kt += 128) {
    bf16x8 kh0 = Kf8[(kfb + (kt >> 4) + w) * 64 + lane];
    bf16x8 kh1 = Kf8[(kfb + (kt >> 4) + 4 + w) * 64 + lane];
    bf16x8 vb0 = Vf8[(((vfb + (kt >> 7)) * 4 + w) * 2 + 0) * 64 + lane];
    bf16x8 vb1 = Vf8[(((vfb + (kt >> 7)) * 4 + w) * 2 + 1) * 64 + lane];
#pragma unroll
    for (int ph = 0; ph < 2; ++ph) {
      bf16x8 kbh = ph ? kh1 : kh0;
      const int c0 = kt + ph * 64 + w * 16;
      const int kg = c0 + l15;
      const int dd = c0 - q0;
      const bool near = (dd >= -96) && (dd <= 96);
      float dsum = 0.f;
      f32x4 s = sinit;
      s = MFMA(qh, kbh, s, 0, 0, 0);
#pragma unroll
      for (int r = 0; r < 4; ++r) {
        float p = fexp2(s[r]);
        Pt[w][q4 * 4 + r][ph * 16 + l15] = bftrunc(p);
        if (near) {
          int qrow = q0 + q4 * 4 + r;
          int dist = (qrow >= kg) ? (qrow - kg) : (kg - qrow);
          dsum += fabsf(p - Elds[dist] * izlds[q4 * 4 + r]);
        } else {
          dsum += p;     // prior underflows to 0 beyond the near band
        }
      }
      dsum += __shfl_xor(dsum, 16);
      dsum += __shfl_xor(dsum, 32);
      if (q4 == 0) Dp[drow + kg] = f2bf(dsum);   // exactly-once per k: plain store
    }
    bf16x8 pa = *(const bf16x8*)&Pt[w][l15][q4 * 8];
    oacc[0] = MFMA(pa, vb0, oacc[0], 0, 0, 0);
    oacc[1] = MFMA(pa, vb1, oacc[1], 0, 0, 0);
  }

  // ---- epilogue: cross-wave O reduce (k-partials), split-bf16 O store ----
  __syncthreads();
  float* Ored = (float*)&Pt[0][0][0];   // [4][16][17] floats = 4352B, fits in Pt
#pragma unroll
  for (int dt = 0; dt < 2; ++dt) {
#pragma unroll
    for (int r = 0; r < 4; ++r)
      Ored[(w * 16 + q4 * 4 + r) * 17 + l15] = oacc[dt][r];
    __syncthreads();
    {
      const int q = tid >> 4, d = tid & 15;
      float v = Ored[q * 17 + d] + Ored[(16 + q) * 17 + d] +
                Ored[(32 + q) * 17 + d] + Ored[(48 + q) * 17 + d];
      const size_t oo = ((size_t)b * LSEQ + q0 + q) * DMODEL + h * HD + dt * 16 + d;
      short hi = f2bf(v);
      Ohb[oo] = hi;
      Olb[oo] = bftrunc(v - bf2f(hi));
    }
    __syncthreads();
  }
}

// ---------------- disc reduction: sum 1024 bf16 partial rows per batch -------
__global__ __launch_bounds__(256) void disc_reduce(
    const short* __restrict__ Dp, float* __restrict__ disc)
{
  __shared__ float red[8][33];
  const int tid = threadIdx.x;
  const int b = blockIdx.x >> 6;              // 128 blocks: 64 per batch
  const int kb = (blockIdx.x & 63) * 32;      // 32 k-columns per block
  const int k = kb + (tid & 31), sg = tid >> 5;
  float acc = 0.f;
  const short* base = Dp + ((size_t)b * 1024 + (size_t)sg * 128) * LSEQ + k;
#pragma unroll 4
  for (int i = 0; i < 128; ++i) acc += bf2f(base[(size_t)i * LSEQ]);
  red[sg][tid & 31] = acc;
  __syncthreads();
  if (tid < 32) {
    float v = 0.f;
#pragma unroll
    for (int s2 = 0; s2 < 8; ++s2) v += red[s2][tid];
    disc[b * LSEQ + kb + tid] = v * (1.0f / ((float)NH * (float)LSEQ));
  }
}

extern "C" void kernel_launch(void* const* d_in, const int* in_sizes, int n_in,
                              void* d_out, int out_size, void* d_ws, size_t ws_size,
                              hipStream_t stream)
{
  const float* x  = (const float*)d_in[0];
  const float* Wq = (const float*)d_in[1];
  const float* bq = (const float*)d_in[2];
  const float* Wk = (const float*)d_in[3];
  const float* bk = (const float*)d_in[4];
  const float* Wv = (const float*)d_in[5];
  const float* bv = (const float*)d_in[6];
  const float* u  = (const float*)d_in[7];
  const float* Wo = (const float*)d_in[8];
  const float* bo = (const float*)d_in[9];

  float* out  = (float*)d_out;
  float* disc = out + (size_t)2 * LSEQ * DMODEL;

  char* w8 = (char*)d_ws;
  const size_t MB = 1u << 20;
  short* Qfb = (short*)(w8);               // 2MB each
  short* Kfb = (short*)(w8 + 2 * MB);
  short* Vfb = (short*)(w8 + 4 * MB);
  short* Ohb = (short*)(w8 + 6 * MB);
  short* Olb = (short*)(w8 + 8 * MB);
  short* Wh  = (short*)(w8 + 10 * MB);                 // 384KB (Wqkv bf16)
  short* Woh = (short*)(w8 + 10 * MB + 393216);        // 128KB
  short* Wol = (short*)(w8 + 10 * MB + 524288);        // 128KB
  float* Eb  = (float*)(w8 + 11 * MB);                 // 64KB
  float* Zb  = (float*)(w8 + 11 * MB + 65536);         // 64KB
  short* Dp  = (short*)(w8 + 12 * MB);                 // 8MB disc partials [2048][2048] bf16

  aux_kernel<<<264, 256, 0, stream>>>(Wq, Wk, Wv, Wo, u, Wh, Woh, Wol, Eb, Zb);
  qkv_gemm<<<dim3(64, 12), 256, 0, stream>>>(x, Wh, bq, bk, bv, Qfb, Kfb, Vfb);
  attn_kernel<<<dim3(128, 8, 2), 256, 0, stream>>>(Qfb, Kfb, Vfb, Eb, Zb,
                                                   Ohb, Olb, Dp);
  disc_reduce<<<128, 256, 0, stream>>>(Dp, disc);
  out_gemm<<<dim3(64, 4), 256, 0, stream>>>(Ohb, Olb, Woh, Wol, bo, out);
}

// Round 2
// 147.598 us; speedup vs baseline: 1.0702x; 1.0618x over previous
//
#include <hip/hip_runtime.h>
#include <hip/hip_bf16.h>
#include <math.h>

#define LSEQ 2048
#define DMODEL 256
#define NH 8
#define HD 32

typedef __attribute__((ext_vector_type(8))) short bf16x8;
typedef __attribute__((ext_vector_type(4))) float f32x4;

#define MFMA __builtin_amdgcn_mfma_f32_16x16x32_bf16

__device__ __forceinline__ short f2bf(float x) {
  __hip_bfloat16 h = __float2bfloat16(x);
  return __builtin_bit_cast(short, h);
}
__device__ __forceinline__ float bf2f(short s) {
  __hip_bfloat16 h = __builtin_bit_cast(__hip_bfloat16, s);
  return __bfloat162float(h);
}
__device__ __forceinline__ short bftrunc(float x) {      // truncating f32->bf16
  return (short)(__builtin_bit_cast(unsigned int, x) >> 16);
}
// bare v_exp_f32 (2^x) — skip OCML denormal fixup (underflowed p contribute 0)
__device__ __forceinline__ float fexp2(float x) {
#if __has_builtin(__builtin_amdgcn_exp2f)
  return __builtin_amdgcn_exp2f(x);
#else
  return __expf(x * 0.6931471805599453f);
#endif
}
__device__ __forceinline__ float flog2(float x) {
#if __has_builtin(__builtin_amdgcn_logf)
  return __builtin_amdgcn_logf(x);
#else
  return __logf(x) * 1.4426950408889634f;
#endif
}

// ---- aux: x -> bf16, Wqkv -> bf16, Wo -> split bf16, prior tables ----
__global__ __launch_bounds__(256) void aux_kernel(
    const float* __restrict__ x,
    const float* __restrict__ Wq, const float* __restrict__ Wk,
    const float* __restrict__ Wv, const float* __restrict__ Wo,
    const float* __restrict__ u,
    short* __restrict__ xh,
    short* __restrict__ Wh,
    short* __restrict__ Woh, short* __restrict__ Wol,
    float* __restrict__ Eb, float* __restrict__ Zb)
{
  __shared__ float Cs[LSEQ];
  __shared__ float part[256];
  const int tid = threadIdx.x;
  if (blockIdx.x < 1024) {            // x (4096x256 fp32) -> bf16, RNE
    const int i4 = (blockIdx.x * 256 + tid) * 4;
    float4 v = *(const float4*)(x + i4);
    *(short4*)(xh + i4) = make_short4(f2bf(v.x), f2bf(v.y), f2bf(v.z), f2bf(v.w));
    return;
  }
  const int bx = blockIdx.x - 1024;
  if (bx < 256) {
    const int i4 = (bx * 256 + tid) * 4;
    if (i4 < 196608) {
      int row = i4 >> 8, col = i4 & 255;
      const float* W = (row < 256) ? Wq : (row < 512) ? Wk : Wv;
      float4 v = *(const float4*)(W + (row & 255) * 256 + col);
      *(short4*)(Wh + i4) = make_short4(f2bf(v.x), f2bf(v.y), f2bf(v.z), f2bf(v.w));
    } else {
      int j = i4 - 196608;
      float4 v = *(const float4*)(Wo + j);
      short h0 = f2bf(v.x), h1 = f2bf(v.y), h2 = f2bf(v.z), h3 = f2bf(v.w);
      *(short4*)(Woh + j) = make_short4(h0, h1, h2, h3);
      *(short4*)(Wol + j) = make_short4(bftrunc(v.x - bf2f(h0)), bftrunc(v.y - bf2f(h1)),
                                        bftrunc(v.z - bf2f(h2)), bftrunc(v.w - bf2f(h3)));
    }
    return;
  }
  const int h = bx - 256;
  const float uu = u[h];
  const float den = 2.0f * (uu * uu + 1e-6f);
  float e[8]; float run = 0.f;
  const int base = tid * 8;
#pragma unroll
  for (int j = 0; j < 8; ++j) {
    float d = (float)(base + j);
    e[j] = __expf(-(d * d) / den);
    run += e[j];
  }
  part[tid] = run;
  __syncthreads();
  for (int off = 1; off < 256; off <<= 1) {
    float v = (tid >= off) ? part[tid - off] : 0.f;
    __syncthreads();
    part[tid] += v;
    __syncthreads();
  }
  float c = part[tid] - run;
#pragma unroll
  for (int j = 0; j < 8; ++j) {
    c += e[j];
    Cs[base + j] = c;
    Eb[h * LSEQ + base + j] = e[j];
  }
  __syncthreads();
  const float E0 = Cs[0];
  for (int i = tid; i < LSEQ; i += 256) {
    float s = Cs[i] + Cs[LSEQ - 1 - i] - E0;
    Zb[h * LSEQ + i] = 1.0f / (s + 1e-6f);
  }
}

// ---------------- fused QKV GEMM (pure bf16 MFMA, LDS-free) ------------------
// x is pre-converted to bf16 (xh) so the hot loop is load+MFMA only.
__global__ __launch_bounds__(256) void qkv_gemm(
    const short* __restrict__ xh,
    const short* __restrict__ Bh,
    const float* __restrict__ bq, const float* __restrict__ bk,
    const float* __restrict__ bv,
    short* __restrict__ Qf, short* __restrict__ Kf, short* __restrict__ Vf)
{
  const int tid = threadIdx.x, w = tid >> 6, lane = tid & 63;
  const int l15 = lane & 15, q4 = lane >> 4;
  const int m0 = blockIdx.x * 64, n0 = blockIdx.y * 64;
  const int mrow = m0 + w * 16 + l15;
  f32x4 acc[4] = {{0,0,0,0},{0,0,0,0},{0,0,0,0},{0,0,0,0}};
  for (int k0 = 0; k0 < 256; k0 += 32) {
    bf16x8 ah = *(const bf16x8*)&xh[(size_t)mrow * 256 + k0 + q4 * 8];
#pragma unroll
    for (int nt = 0; nt < 4; ++nt) {
      const size_t bi = (size_t)(n0 + nt * 16 + l15) * 256 + k0 + q4 * 8;
      bf16x8 bh = *(const bf16x8*)&Bh[bi];
      acc[nt] = MFMA(ah, bh, acc[nt], 0, 0, 0);
    }
  }
  const int type = n0 >> 8;        // 0=Q 1=K 2=V
  const int n0l = n0 & 255;
  const float* bias = (type == 0) ? bq : (type == 1) ? bk : bv;
  const float qls = 0.25503489f;   // (1/sqrt(32)) * log2(e)
#pragma unroll
  for (int nt = 0; nt < 4; ++nt) {
    const int col = n0l + nt * 16 + l15;
    const float bvv = bias[col];
    const int hh = col >> 5, dloc = col & 31;
#pragma unroll
    for (int r = 0; r < 4; ++r) {
      const int m = m0 + w * 16 + q4 * 4 + r;
      float v = acc[nt][r] + bvv;
      const int bb = m >> 11, mm = m & 2047, rr = mm & 15;
      if (type == 2) {
        const int kt128 = mm >> 7, low7 = mm & 127;
        const int wv = (low7 >> 4) & 3, ph = low7 >> 6;
        const int c = ph * 16 + rr;
        const size_t idx =
          ((((((size_t)bb * 8 + hh) * 16 + kt128) * 4 + wv) * 2 + (dloc >> 4)) * 64
           + (c >> 3) * 16 + (dloc & 15)) * 8 + (c & 7);
        Vf[idx] = f2bf(v);
      } else if (type == 0) {
        const int qblk = mm >> 5, rg = (mm >> 4) & 1;
        const size_t idx =
          (((((size_t)bb * 8 + hh) * 64 + qblk) * 2 + rg) * 64
           + (dloc >> 3) * 16 + rr) * 8 + (dloc & 7);
        Qf[idx] = f2bf(v * qls);
      } else {
        const int g = mm >> 4;
        const size_t idx =
          ((((size_t)bb * 8 + hh) * 128 + g) * 64
           + (dloc >> 3) * 16 + rr) * 8 + (dloc & 7);
        Kf[idx] = f2bf(v);
      }
    }
  }
}

// ---------------- output GEMM (split-bf16 MFMA, fp32 out) --------------------
// 64x32 tiles, grid (64,8): 512 blocks = 2 blocks/CU = 8 waves/CU (was 4).
__global__ __launch_bounds__(256) void out_gemm(
    const short* __restrict__ Ah, const short* __restrict__ Al,
    const short* __restrict__ Bh, const short* __restrict__ Bl,
    const float* __restrict__ bias, float* __restrict__ C)
{
  const int tid = threadIdx.x, w = tid >> 6, lane = tid & 63;
  const int l15 = lane & 15, q4 = lane >> 4;
  const int m0 = blockIdx.x * 64, n0 = blockIdx.y * 32;
  const int mrow = m0 + w * 16 + l15;
  f32x4 acc[2] = {{0,0,0,0},{0,0,0,0}};
  for (int k0 = 0; k0 < 256; k0 += 32) {
    bf16x8 ah = *(const bf16x8*)&Ah[(size_t)mrow * 256 + k0 + q4 * 8];
    bf16x8 al = *(const bf16x8*)&Al[(size_t)mrow * 256 + k0 + q4 * 8];
#pragma unroll
    for (int nt = 0; nt < 2; ++nt) {
      const size_t bi = (size_t)(n0 + nt * 16 + l15) * 256 + k0 + q4 * 8;
      bf16x8 bh = *(const bf16x8*)&Bh[bi];
      bf16x8 bl = *(const bf16x8*)&Bl[bi];
      acc[nt] = MFMA(ah, bh, acc[nt], 0, 0, 0);
      acc[nt] = MFMA(al, bh, acc[nt], 0, 0, 0);
      acc[nt] = MFMA(ah, bl, acc[nt], 0, 0, 0);
    }
  }
#pragma unroll
  for (int nt = 0; nt < 2; ++nt) {
    const int col = n0 + nt * 16 + l15;
    const float bvv = bias[col];
#pragma unroll
    for (int r = 0; r < 4; ++r) {
      const int m = m0 + w * 16 + q4 * 4 + r;
      C[(size_t)m * 256 + col] = acc[nt][r] + bvv;
    }
  }
}

// ---------------- barrier-free MFMA flash attention + discrepancy ------------
// 2 independent 16-row q-tiles per block (shared K/V loads): two independent
// MFMA->exp2 chains per wave fill each other's latency stalls (VALU-issue
// floor ~18us; round-1 measured VALUBusy 39% => ~60% of slots were stalls).
// 1024 blocks = 4 blocks/CU (16 waves/CU at <=128 VGPR). Dp partial rows now
// sum 32 q-rows -> Dp halves to 4MB.
__global__ __launch_bounds__(256, 4) void attn_kernel(
    const short* __restrict__ Qf, const short* __restrict__ Kf,
    const short* __restrict__ Vf,
    const float* __restrict__ Eb, const float* __restrict__ Zb,
    short* __restrict__ Ohb, short* __restrict__ Olb,
    short* __restrict__ Dp)
{
  __shared__ short Pt[2][4][16][40];   // per-tile per-wave P tile (reused as Ored)
  __shared__ float Elds[192];
  __shared__ float lpart[2][4][16];
  __shared__ float izlds[32];

  const int tid = threadIdx.x, w = tid >> 6, lane = tid & 63;
  const int l15 = lane & 15, q4 = lane >> 4;
  // ---- XCD swizzle: flat = x + 64*(y + 8*z); xcd = flat&7 ----
  const int flat = blockIdx.x + 64 * (blockIdx.y + 8 * blockIdx.z);
  const int slot = flat >> 3;                       // 0..127
  const int g = (flat & 7) | ((slot >> 6) << 3);    // 0..15: (b,h) stays on one XCD
  const int h = g & 7, b = g >> 3;
  const int qpair = slot & 63;
  const int q0 = qpair * 32;                        // tile A: q0..q0+15, B: +16
  const int bh = b * NH + h;

  if (tid < 192) Elds[tid] = Eb[h * LSEQ + tid];
  if (tid < 32)  izlds[tid] = Zb[h * LSEQ + q0 + tid];

  const bf16x8* Qf8 = (const bf16x8*)Qf;
  const bf16x8* Kf8 = (const bf16x8*)Kf;
  const bf16x8* Vf8 = (const bf16x8*)Vf;

  bf16x8 qhA = Qf8[((size_t)bh * 128 + qpair * 2 + 0) * 64 + lane];
  bf16x8 qhB = Qf8[((size_t)bh * 128 + qpair * 2 + 1) * 64 + lane];
  __syncthreads();

  const size_t kfb = (size_t)bh * 128;   // K group base
  const size_t vfb = (size_t)bh * 16;    // V kt128 base

  // ---- pass 1: per-wave k-partial row sums of 2^s (both tiles) ----
  float lacA[4] = {0.f, 0.f, 0.f, 0.f};
  float lacB[4] = {0.f, 0.f, 0.f, 0.f};
#pragma unroll 2
  for (int kt = 0; kt < LSEQ; kt += 128) {
    bf16x8 k0 = Kf8[(kfb + (kt >> 4) + w) * 64 + lane];
    bf16x8 k1 = Kf8[(kfb + (kt >> 4) + 4 + w) * 64 + lane];
    f32x4 sA0 = {0.f,0.f,0.f,0.f}; sA0 = MFMA(qhA, k0, sA0, 0, 0, 0);
    f32x4 sB0 = {0.f,0.f,0.f,0.f}; sB0 = MFMA(qhB, k0, sB0, 0, 0, 0);
    f32x4 sA1 = {0.f,0.f,0.f,0.f}; sA1 = MFMA(qhA, k1, sA1, 0, 0, 0);
    f32x4 sB1 = {0.f,0.f,0.f,0.f}; sB1 = MFMA(qhB, k1, sB1, 0, 0, 0);
#pragma unroll
    for (int r = 0; r < 4; ++r) {
      lacA[r] += fexp2(sA0[r]) + fexp2(sA1[r]);
      lacB[r] += fexp2(sB0[r]) + fexp2(sB1[r]);
    }
  }
#pragma unroll
  for (int r = 0; r < 4; ++r) {
    float a = lacA[r], bb2 = lacB[r];
    a += __shfl_xor(a, 1); a += __shfl_xor(a, 2);
    a += __shfl_xor(a, 4); a += __shfl_xor(a, 8);
    bb2 += __shfl_xor(bb2, 1); bb2 += __shfl_xor(bb2, 2);
    bb2 += __shfl_xor(bb2, 4); bb2 += __shfl_xor(bb2, 8);
    lacA[r] = a; lacB[r] = bb2;
  }
  if (l15 == 0) {
#pragma unroll
    for (int r = 0; r < 4; ++r) {
      lpart[0][w][q4 * 4 + r] = lacA[r];
      lpart[1][w][q4 * 4 + r] = lacB[r];
    }
  }
  __syncthreads();
  f32x4 sinitA, sinitB;
#pragma unroll
  for (int r = 0; r < 4; ++r) {
    const int qi = q4 * 4 + r;
    sinitA[r] = -flog2(lpart[0][0][qi] + lpart[0][1][qi] + lpart[0][2][qi] + lpart[0][3][qi]);
    sinitB[r] = -flog2(lpart[1][0][qi] + lpart[1][1][qi] + lpart[1][2][qi] + lpart[1][3][qi]);
  }

  // ---- pass 2: p = 2^(s + sinit), disc column partials, O += P*V ----
  const size_t drow = (size_t)(g * 64 + qpair) * LSEQ;
  f32x4 oaccA[2] = {{0,0,0,0},{0,0,0,0}};
  f32x4 oaccB[2] = {{0,0,0,0},{0,0,0,0}};
#pragma unroll 2
  for (int kt = 0; kt < LSEQ; kt += 128) {
    bf16x8 kh0 = Kf8[(kfb + (kt >> 4) + w) * 64 + lane];
    bf16x8 kh1 = Kf8[(kfb + (kt >> 4) + 4 + w) * 64 + lane];
    bf16x8 vb0 = Vf8[(((vfb + (kt >> 7)) * 4 + w) * 2 + 0) * 64 + lane];
    bf16x8 vb1 = Vf8[(((vfb + (kt >> 7)) * 4 + w) * 2 + 1) * 64 + lane];
#pragma unroll
    for (int ph = 0; ph < 2; ++ph) {
      bf16x8 kbh = ph ? kh1 : kh0;
      const int c0 = kt + ph * 64 + w * 16;
      const int kg = c0 + l15;
      const int ddA = c0 - q0;
      const int ddB = ddA - 16;
      const bool nearA = (ddA >= -96) && (ddA <= 96);
      const bool nearB = (ddB >= -96) && (ddB <= 96);
      f32x4 sA = sinitA; sA = MFMA(qhA, kbh, sA, 0, 0, 0);
      f32x4 sB = sinitB; sB = MFMA(qhB, kbh, sB, 0, 0, 0);
      float dsum = 0.f;
#pragma unroll
      for (int r = 0; r < 4; ++r) {
        float pA = fexp2(sA[r]);
        Pt[0][w][q4 * 4 + r][ph * 16 + l15] = bftrunc(pA);
        if (nearA) {
          int qrow = q0 + q4 * 4 + r;
          int dist = (qrow >= kg) ? (qrow - kg) : (kg - qrow);
          dsum += fabsf(pA - Elds[dist] * izlds[q4 * 4 + r]);
        } else {
          dsum += pA;     // prior underflows to 0 beyond the near band
        }
      }
#pragma unroll
      for (int r = 0; r < 4; ++r) {
        float pB = fexp2(sB[r]);
        Pt[1][w][q4 * 4 + r][ph * 16 + l15] = bftrunc(pB);
        if (nearB) {
          int qrow = q0 + 16 + q4 * 4 + r;
          int dist = (qrow >= kg) ? (qrow - kg) : (kg - qrow);
          dsum += fabsf(pB - Elds[dist] * izlds[16 + q4 * 4 + r]);
        } else {
          dsum += pB;
        }
      }
      dsum += __shfl_xor(dsum, 16);
      dsum += __shfl_xor(dsum, 32);
      if (q4 == 0) Dp[drow + kg] = f2bf(dsum);   // exactly-once per k: plain store
    }
    bf16x8 paA = *(const bf16x8*)&Pt[0][w][l15][q4 * 8];
    bf16x8 paB = *(const bf16x8*)&Pt[1][w][l15][q4 * 8];
    oaccA[0] = MFMA(paA, vb0, oaccA[0], 0, 0, 0);
    oaccB[0] = MFMA(paB, vb0, oaccB[0], 0, 0, 0);
    oaccA[1] = MFMA(paA, vb1, oaccA[1], 0, 0, 0);
    oaccB[1] = MFMA(paB, vb1, oaccB[1], 0, 0, 0);
  }

  // ---- epilogue: cross-wave O reduce (k-partials), split-bf16 O store ----
  __syncthreads();
  float* Ored = (float*)&Pt[0][0][0][0];   // [4][16][17] floats = 4352B, fits
  auto store_tile = [&](f32x4 o, int trow, int dt) {
#pragma unroll
    for (int r = 0; r < 4; ++r)
      Ored[(w * 16 + q4 * 4 + r) * 17 + l15] = o[r];
    __syncthreads();
    {
      const int q = tid >> 4, d = tid & 15;
      float v = Ored[q * 17 + d] + Ored[(16 + q) * 17 + d] +
                Ored[(32 + q) * 17 + d] + Ored[(48 + q) * 17 + d];
      const size_t oo = ((size_t)b * LSEQ + q0 + trow + q) * DMODEL + h * HD + dt * 16 + d;
      short hi = f2bf(v);
      Ohb[oo] = hi;
      Olb[oo] = bftrunc(v - bf2f(hi));
    }
    __syncthreads();
  };
  store_tile(oaccA[0], 0, 0);
  store_tile(oaccA[1], 0, 1);
  store_tile(oaccB[0], 16, 0);
  store_tile(oaccB[1], 16, 1);
}

// ---------------- disc reduction: sum 512 bf16 partial rows per batch --------
__global__ __launch_bounds__(256) void disc_reduce(
    const short* __restrict__ Dp, float* __restrict__ disc)
{
  __shared__ float red[8][33];
  const int tid = threadIdx.x;
  const int b = blockIdx.x >> 6;              // 128 blocks: 64 per batch
  const int kb = (blockIdx.x & 63) * 32;      // 32 k-columns per block
  const int k = kb + (tid & 31), sg = tid >> 5;
  float acc = 0.f;
  const short* base = Dp + ((size_t)b * 512 + (size_t)sg * 64) * LSEQ + k;
#pragma unroll 4
  for (int i = 0; i < 64; ++i) acc += bf2f(base[(size_t)i * LSEQ]);
  red[sg][tid & 31] = acc;
  __syncthreads();
  if (tid < 32) {
    float v = 0.f;
#pragma unroll
    for (int s2 = 0; s2 < 8; ++s2) v += red[s2][tid];
    disc[b * LSEQ + kb + tid] = v * (1.0f / ((float)NH * (float)LSEQ));
  }
}

extern "C" void kernel_launch(void* const* d_in, const int* in_sizes, int n_in,
                              void* d_out, int out_size, void* d_ws, size_t ws_size,
                              hipStream_t stream)
{
  const float* x  = (const float*)d_in[0];
  const float* Wq = (const float*)d_in[1];
  const float* bq = (const float*)d_in[2];
  const float* Wk = (const float*)d_in[3];
  const float* bk = (const float*)d_in[4];
  const float* Wv = (const float*)d_in[5];
  const float* bv = (const float*)d_in[6];
  const float* u  = (const float*)d_in[7];
  const float* Wo = (const float*)d_in[8];
  const float* bo = (const float*)d_in[9];

  float* out  = (float*)d_out;
  float* disc = out + (size_t)2 * LSEQ * DMODEL;

  char* w8 = (char*)d_ws;
  const size_t MB = 1u << 20;
  short* Qfb = (short*)(w8);               // 2MB each
  short* Kfb = (short*)(w8 + 2 * MB);
  short* Vfb = (short*)(w8 + 4 * MB);
  short* Ohb = (short*)(w8 + 6 * MB);
  short* Olb = (short*)(w8 + 8 * MB);
  short* Wh  = (short*)(w8 + 10 * MB);                 // 384KB (Wqkv bf16)
  short* Woh = (short*)(w8 + 10 * MB + 393216);        // 128KB
  short* Wol = (short*)(w8 + 10 * MB + 524288);        // 128KB
  float* Eb  = (float*)(w8 + 11 * MB);                 // 64KB
  float* Zb  = (float*)(w8 + 11 * MB + 65536);         // 64KB
  short* xh  = (short*)(w8 + 12 * MB);                 // 2MB (x bf16)
  short* Dp  = (short*)(w8 + 14 * MB);                 // 4MB disc partials [1024][2048] bf16

  aux_kernel<<<1288, 256, 0, stream>>>(x, Wq, Wk, Wv, Wo, u, xh, Wh, Woh, Wol, Eb, Zb);
  qkv_gemm<<<dim3(64, 12), 256, 0, stream>>>(xh, Wh, bq, bk, bv, Qfb, Kfb, Vfb);
  attn_kernel<<<dim3(64, 8, 2), 256, 0, stream>>>(Qfb, Kfb, Vfb, Eb, Zb,
                                                  Ohb, Olb, Dp);
  disc_reduce<<<128, 256, 0, stream>>>(Dp, disc);
  out_gemm<<<dim3(64, 8), 256, 0, stream>>>(Ohb, Olb, Woh, Wol, bo, out);
}